// Round 15
// baseline (777.439 us; speedup 1.0000x reference)
//
#include <hip/hip_runtime.h>
#include <math.h>

// ---------------------------------------------------------------------------
// QFullResnetBlock: two quantum passes (13x 12-qubit sims + 1x 4-qubit sim per
// batch elem) + groupnorm/time-FiLM/swish glue + residual.
//
// 12-qubit sim: FOUR waves per sim (one 256-thread WG = 1 sim), 16 amps per
// thread as packed-FP32 pairs: f2 R[8], I[8] = 16 VGPR state.
// Amplitude amp (12 bits) = (wq << 10) | (lane << 4) | (j << 1) | e :
//   bit  0     = e    (element of the f2)
//   bits 1..3  = j    (8 register pairs)
//   bits 4..9  = lane (lane bit L = amp bit 4+L)
//   bits 10,11 = wq   (wave within sim; 2 masked LDS exchanges per layer)
// Qubit w lives at amp bit (11-w).
//
// R14 status: 537us total, per-dispatch 307; VALUBusy 79%, occupancy pinned
// at ~54% (=~4.4 waves/SIMD) though VGPR 44 allows 11 and LDS 17408 allows
// 8 WGs/CU. Hypothesis: the SPI schedules to the DECLARED min-waves target
// (launch_bounds 2nd arg = 4). R15: __launch_bounds__(256, 8) -> VGPR budget
// 512/8 = 64 >= demand 44 (no spill possible), LDS 8*17408 = 139KB <= 160KB.
// Single-variable A/B on the occupancy-cap theory.
//
// Cross-lane op map: mask1->DPP 0xB1, mask2->DPP 0x4E, mask4->swz 0x101F,
// mask8->DPP row_ror:8, mask16->swz 0x401F, mask32->ds_bpermute.
//
// R10 LESSON (kept): inline-asm with two "+v" operands initialized from the
// SAME value can coalesce onto one physical register -> permlane_swap
// degenerates. psum16/psum32 use "=&v" early-clobber + explicit movs.
//
// R13 LESSON (kept): doubling LDS (fused exchange) cut occupancy 54->43.5%
// -> occupancy beats barrier count at this operating point.
//
// OCCUPANCY MODEL (R0-R14 measured): residency tracks VGPR_Count AND the
// declared min-waves: <=64 VGPR -> 4+ waves/SIMD; 65..128 -> 2; >128 -> 1.
// Spill signature: WRITE_SIZE >> 2 MB (R1: 465 MB, R4: 3.9 GB).
//
// Gate pattern per layer l, group g, m=0..3 (amp-bit positions):
//   target bit pt = 4g+m, control bit pc = (4g+8+m)%12
//   g=0: tgt e,j0,j1,j2 (local);    ctrl lane4,lane5,wq0,wq1 (uniform folds)
//   g=1: tgt lane0..3 (exchanges);  ctrl e,j0,j1,j2 (element/reg masks)
//   g=2: tgt lane4,lane5 (swz16/bperm32) + wq0,wq1 (LDS); ctrl lane0..3
// ---------------------------------------------------------------------------

#define PI_F 3.14159265358979323846f

#define DPP_XOR1 0xB1
#define DPP_XOR2 0x4E
#define DPP_XOR8 0x128

typedef float f2 __attribute__((ext_vector_type(2)));

template<int CTRL>
__device__ __forceinline__ float dppf(float x)
{
    return __int_as_float(__builtin_amdgcn_update_dpp(
        __float_as_int(x), __float_as_int(x), CTRL, 0xF, 0xF, false));
}

template<int CTRL>
__device__ __forceinline__ f2 dpp2v(f2 v)
{
    f2 r;
    r[0] = dppf<CTRL>(v[0]);
    r[1] = dppf<CTRL>(v[1]);
    return r;
}

__device__ __forceinline__ float swz4f(float x)
{
    // ds_swizzle BitMode xor_mask=4: offset = (4<<10) | 0x1F
    return __int_as_float(__builtin_amdgcn_ds_swizzle(__float_as_int(x), 0x101F));
}

__device__ __forceinline__ f2 swz4v(f2 v)
{
    f2 r;
    r[0] = swz4f(v[0]);
    r[1] = swz4f(v[1]);
    return r;
}

__device__ __forceinline__ float swz16f(float x)
{
    // ds_swizzle BitMode xor_mask=16: offset = (16<<10) | 0x1F
    return __int_as_float(__builtin_amdgcn_ds_swizzle(__float_as_int(x), 0x401F));
}

__device__ __forceinline__ f2 swz16v(f2 v)
{
    f2 r;
    r[0] = swz16f(v[0]);
    r[1] = swz16f(v[1]);
    return r;
}

// x + shfl_xor(x,16): one permlane16_swap over two GUARANTEED-DISTINCT regs
// (early-clobber outputs; R10 aliasing lesson). Orientation-independent.
__device__ __forceinline__ float psum16(float x)
{
    float c, d;
    asm("v_mov_b32 %0, %2\n\t"
        "v_mov_b32 %1, %2\n\t"
        "v_permlane16_swap_b32 %0, %1"
        : "=&v"(c), "=&v"(d)
        : "v"(x));
    return c + d;
}

__device__ __forceinline__ float psum32(float x)
{
    float c, d;
    asm("v_mov_b32 %0, %2\n\t"
        "v_mov_b32 %1, %2\n\t"
        "v_permlane32_swap_b32 %0, %1"
        : "=&v"(c), "=&v"(d)
        : "v"(x));
    return c + d;
}

// ---- g=0 ------------------------------------------------------------------
// Fused CRZ group: 4 diagonal gates, ctrl lane4/lane5/wq0/wq1 (thread-uniform
// folds), target amp bits 0..3 = (j<<1)|e. M[15-t] = conj(M[t]).
// Multiplier built once as packed f2 (MrV/MiV over t=0..7); conj half applied
// via op_sel swap with signs folded into the FMA pattern.
__device__ __forceinline__ void crz_g0_fused(const float* a, f2* R, f2* I,
                                             int lane, int wq)
{
    float gr[4], gi[4];
#pragma unroll
    for (int m = 0; m < 4; ++m) {
        bool cb;
        if      (m == 0) cb = (lane >> 4) & 1;
        else if (m == 1) cb = (lane >> 5) & 1;
        else if (m == 2) cb = wq & 1;
        else             cb = (wq >> 1) & 1;
        gr[m] = cb ? a[2 * m]     : 1.0f;
        gi[m] = cb ? a[2 * m + 1] : 0.0f;
    }
    float u0 = gr[1] * gr[0], v0 = gi[1] * gi[0];
    float w0 = gr[1] * gi[0], z0 = gi[1] * gr[0];
    float p01r[2] = { u0 - v0, u0 + v0 };
    float p01i[2] = { -(w0 + z0), w0 - z0 };
    float u1 = gr[3] * gr[2], v1 = gi[3] * gi[2];
    float w1 = gr[3] * gi[2], z1 = gi[3] * gr[2];
    float p23r[2] = { u1 - v1, u1 + v1 };
    float p23i[2] = { -(w1 + z1), w1 - z1 };

    // table: MrV[p] = {M[2p].r, M[2p+1].r}, MiV[p] = {M[2p].i, M[2p+1].i}
    f2 MrV[4], MiV[4];
#pragma unroll
    for (int p = 0; p < 4; ++p) {
#pragma unroll
        for (int e = 0; e < 2; ++e) {
            const int t = 2 * p + e;
            const int t10 = t & 3, t2 = (t >> 2) & 1;
            float br = (t10 == 0 || t10 == 3) ? p01r[0] : p01r[1];
            float bi = (t10 == 0) ? p01i[0] : (t10 == 1) ? p01i[1]
                     : (t10 == 2) ? -p01i[1] : -p01i[0];
            MrV[p][e] = p23r[t2] * br - p23i[t2] * bi;
            MiV[p][e] = p23r[t2] * bi + p23i[t2] * br;
        }
    }
    // j < 4: direct
#pragma unroll
    for (int j = 0; j < 4; ++j) {
        f2 mr = MrV[j], mi = MiV[j];
        f2 r = R[j], im = I[j];
        R[j] = mr * r - mi * im;
        I[j] = mr * im + mi * r;
    }
    // j >= 4: conj-mirror -> R' = swap(Mr)*r + swap(Mi)*im ;
    //                        I' = swap(Mr)*im - swap(Mi)*r
#pragma unroll
    for (int j = 4; j < 8; ++j) {
        f2 mr = __builtin_shufflevector(MrV[7 - j], MrV[7 - j], 1, 0);
        f2 mi = __builtin_shufflevector(MiV[7 - j], MiV[7 - j], 1, 0);
        f2 r = R[j], im = I[j];
        R[j] = mr * r + mi * im;
        I[j] = mr * im - mi * r;
    }
}

// CRX within the pair (target = e), uniform folded coeff
__device__ __forceinline__ void crx_pair(float cg, float sg, f2* R, f2* I)
{
#pragma unroll
    for (int j = 0; j < 8; ++j) {
        f2 r = R[j], im = I[j];
        f2 rs = __builtin_shufflevector(r, r, 1, 0);
        f2 is = __builtin_shufflevector(im, im, 1, 0);
        R[j] = cg * r + sg * is;
        I[j] = cg * im - sg * rs;
    }
}

// CRX between registers j and j|M (target = j bit), uniform coeff
template<int M>
__device__ __forceinline__ void crx_elem(float cg, float sg, f2* R, f2* I)
{
#pragma unroll
    for (int j = 0; j < 8; ++j) {
        if (j & M) continue;
        const int p = j | M;
        f2 r0 = R[j], i0 = I[j], r1 = R[p], i1 = I[p];
        R[j] = cg * r0 + sg * i1;  I[j] = cg * i0 - sg * r1;
        R[p] = cg * r1 + sg * i0;  I[p] = cg * i1 - sg * r0;
    }
}

// ---- g=1 ------------------------------------------------------------------
// CRZ, ctrl = e (hi element only), sign by lane bit 0
__device__ __forceinline__ void crz_e(float cg, float ss, f2* R, f2* I)
{
    const f2 mrv = {1.0f, cg};
    const f2 miv = {0.0f, ss};
#pragma unroll
    for (int j = 0; j < 8; ++j) {
        f2 r = R[j], im = I[j];
        R[j] = mrv * r - miv * im;
        I[j] = mrv * im + miv * r;
    }
}

// CRZ, ctrl = j bit CB, thread-uniform (cg, ss)
template<int CB>
__device__ __forceinline__ void crz_ctrlj(float cg, float ss, f2* R, f2* I)
{
#pragma unroll
    for (int j = 0; j < 8; ++j) {
        if (!((j >> CB) & 1)) continue;
        f2 r = R[j], im = I[j];
        R[j] = cg * r - ss * im;
        I[j] = cg * im + ss * r;
    }
}

// CRX, ctrl = e (hi element), target = lane bit 0 (DPP xor1, VALU pipe)
__device__ __forceinline__ void crx_sh_e(float cg, float sg, f2* R, f2* I)
{
    const f2 cgv = {1.0f, cg};
    const f2 sgv = {0.0f, sg};
#pragma unroll
    for (int j = 0; j < 8; ++j) {
        f2 br = dpp2v<DPP_XOR1>(R[j]);
        f2 bi = dpp2v<DPP_XOR1>(I[j]);
        f2 r = R[j], im = I[j];
        R[j] = cgv * r + sgv * bi;
        I[j] = cgv * im - sgv * br;
    }
}

// CRX, ctrl = j bit CB, target lane exchange via DPP (VALU pipe)
template<int CB, int CTRL>
__device__ __forceinline__ void crx_shj_dpp(float cg, float sg, f2* R, f2* I)
{
#pragma unroll
    for (int j = 0; j < 8; ++j) {
        if (!((j >> CB) & 1)) continue;
        f2 br = dpp2v<CTRL>(R[j]);
        f2 bi = dpp2v<CTRL>(I[j]);
        f2 r = R[j], im = I[j];
        R[j] = cg * r + sg * bi;
        I[j] = cg * im - sg * br;
    }
}

// CRX, ctrl = j bit CB, target = lane bit 2 (mask 4: ds_swizzle, DS pipe)
template<int CB>
__device__ __forceinline__ void crx_shj_swz4(float cg, float sg, f2* R, f2* I)
{
#pragma unroll
    for (int j = 0; j < 8; ++j) {
        if (!((j >> CB) & 1)) continue;
        f2 br = swz4v(R[j]);
        f2 bi = swz4v(I[j]);
        f2 r = R[j], im = I[j];
        R[j] = cg * r + sg * bi;
        I[j] = cg * im - sg * br;
    }
}

// ---- g=2 ------------------------------------------------------------------
// Fused CRZ group: all 4 gates thread-uniform ctrl + sign -> ONE multiplier.
__device__ __forceinline__ void crz_g2_fused(const float* a, f2* R, f2* I,
                                             int lane, int wq)
{
    float s0 = ((lane >> 4) & 1) ? a[1] : -a[1];
    bool  c0 = lane & 1;
    float f0r = c0 ? a[0] : 1.0f, f0i = c0 ? s0 : 0.0f;
    float s1 = ((lane >> 5) & 1) ? a[3] : -a[3];
    bool  c1 = (lane >> 1) & 1;
    float f1r = c1 ? a[2] : 1.0f, f1i = c1 ? s1 : 0.0f;
    float s2 = (wq & 1) ? a[5] : -a[5];
    bool  c2 = (lane >> 2) & 1;
    float f2r = c2 ? a[4] : 1.0f, f2i = c2 ? s2 : 0.0f;
    float s3 = ((wq >> 1) & 1) ? a[7] : -a[7];
    bool  c3 = (lane >> 3) & 1;
    float f3r = c3 ? a[6] : 1.0f, f3i = c3 ? s3 : 0.0f;
    float t01r = f0r * f1r - f0i * f1i, t01i = f0r * f1i + f0i * f1r;
    float t23r = f2r * f3r - f2i * f3i, t23i = f2r * f3i + f2i * f3r;
    float Pr = t01r * t23r - t01i * t23i;
    float Pi = t01r * t23i + t01i * t23r;
#pragma unroll
    for (int j = 0; j < 8; ++j) {
        f2 r = R[j], im = I[j];
        R[j] = Pr * r - Pi * im;
        I[j] = Pr * im + Pi * r;
    }
}

// CRX, uniform folded ctrl, target = lane bit 4 via ds_swizzle xor16 (DS)
__device__ __forceinline__ void crx_swz16_all(float cg, float sg, f2* R, f2* I)
{
#pragma unroll
    for (int j = 0; j < 8; ++j) {
        f2 br = swz16v(R[j]);
        f2 bi = swz16v(I[j]);
        f2 r = R[j], im = I[j];
        R[j] = cg * r + sg * bi;
        I[j] = cg * im - sg * br;
    }
}

// CRX, uniform folded ctrl, target = lane bit 5 via ds_bpermute (DS pipe;
// wave-wide lane indexing on CDNA). pa = (lane ^ 32) << 2.
__device__ __forceinline__ void crx_bperm32(float cg, float sg, f2* R, f2* I,
                                            int pa)
{
#pragma unroll
    for (int j = 0; j < 8; ++j) {
        f2 br, bi;
        br[0] = __int_as_float(__builtin_amdgcn_ds_bpermute(pa, __float_as_int(R[j][0])));
        br[1] = __int_as_float(__builtin_amdgcn_ds_bpermute(pa, __float_as_int(R[j][1])));
        bi[0] = __int_as_float(__builtin_amdgcn_ds_bpermute(pa, __float_as_int(I[j][0])));
        bi[1] = __int_as_float(__builtin_amdgcn_ds_bpermute(pa, __float_as_int(I[j][1])));
        f2 r = R[j], im = I[j];
        R[j] = cg * r + sg * bi;
        I[j] = cg * im - sg * br;
    }
}

__global__ void __launch_bounds__(256, 8)
qpass12_kernel(const float* __restrict__ inp, const float* __restrict__ cs,
               float* __restrict__ outp)
{
    // exchange buffer: [wq 0..3][row 0..31] x 17 f2 (16 data + 1 pad).
    // 4*32*17 f2 = 17408 B -> 8 WGs/CU fit (139264 <= 163840).
    __shared__ f2 xbufv[4 * 32 * 17];
    float* xbuff = reinterpret_cast<float*>(xbufv);
    const int ts   = threadIdx.x;
    const int wq   = ts >> 6;             // amp bits 10 (wq&1), 11 (wq>>1)
    const int lane = ts & 63;             // amp bits 4..9
    const int sim  = blockIdx.x;
    const int ci = sim % 13;
    const int b  = sim / 13;
    const float* csc = cs + ci * 144;     // 72 gates * (cos,sin)
    const int ibase = b * 160 + ci * 3;   // (B,2,2,40) flat; sp stride 40

    // data angles: qubit w <- inp[b, w/3, (w%3)+3*ci]
    float cw[12], sw[12];
#pragma unroll
    for (int w = 0; w < 12; ++w) {
        float x = inp[ibase + (w / 3) * 40 + (w % 3)];
        __sincosf(0.5f * x, &sw[w], &cw[w]);
    }

    // product-state init: qubit w at amp bit 11-w.
    float pref = ((wq >> 1) ? sw[0] : cw[0]) * ((wq & 1) ? sw[1] : cw[1]);
#pragma unroll
    for (int w = 2; w < 8; ++w)
        pref *= ((lane >> (7 - w)) & 1) ? sw[w] : cw[w];

    const int pl = (__popc(lane) + __popc(wq)) & 3;
    float oa = (pl == 0) ? 1.0f : (pl == 2) ? -1.0f : 0.0f;
    float ob = (pl == 1) ? -1.0f : (pl == 3) ? 1.0f : 0.0f;

    f2 R[8], I[8];
#pragma unroll
    for (int j = 0; j < 8; ++j) {
        float base = pref * ((j & 4) ? sw[8] : cw[8]) *
                     ((j & 2) ? sw[9] : cw[9]) * ((j & 1) ? sw[10] : cw[10]);
        f2 v2 = { base * cw[11], base * sw[11] };
        const int q0 = __popc(j) & 3;
        const int q1 = (q0 + 1) & 3;
        const float c0l = (q0 == 0) ? oa : (q0 == 1) ? ob : (q0 == 2) ? -oa : -ob;
        const float c1l = (q0 == 0) ? ob : (q0 == 1) ? -oa : (q0 == 2) ? -ob : oa;
        const float c0h = (q1 == 0) ? oa : (q1 == 1) ? ob : (q1 == 2) ? -oa : -ob;
        const float c1h = (q1 == 0) ? ob : (q1 == 1) ? -oa : (q1 == 2) ? -ob : oa;
        R[j] = f2{ v2[0] * c0l, v2[1] * c0h };
        I[j] = f2{ v2[0] * c1l, v2[1] * c1h };
    }

    // cross-wave exchange addressing
    const bool act2 = (lane >> 2) & 1;
    const bool act3 = (lane >> 3) & 1;
    const int ai2 = ((lane >> 3) << 2) | (lane & 3);
    const int ai3 = ((lane >> 4) << 3) | (lane & 7);
    const int pa  = ((lane ^ 32) << 2);   // bpermute partner byte addr
    f2* xw2 = &xbufv[(wq * 32 + ai2) * 17];
    f2* xr2 = &xbufv[((wq ^ 1) * 32 + ai2) * 17];
    f2* xw3 = &xbufv[(wq * 32 + ai3) * 17];
    f2* xr3 = &xbufv[((wq ^ 2) * 32 + ai3) * 17];

#pragma unroll 1
    for (int l = 0; l < 3; ++l) {
        const float* a = csc + l * 48;

        // ---- g=0: tgt e,j0,j1,j2 ; ctrl lane4,lane5,wq0,wq1 ----
        crz_g0_fused(a, R, I, lane, wq);
        { bool cb = (lane >> 4) & 1;
          crx_pair(cb ? a[ 8] : 1.0f, cb ? a[ 9] : 0.0f, R, I); }
        { bool cb = (lane >> 5) & 1;
          crx_elem<1>(cb ? a[10] : 1.0f, cb ? a[11] : 0.0f, R, I); }
        // wq-controlled: WAVE-UNIFORM skip (identity when ctrl clear)
        if (wq & 1)
            crx_elem<2>(a[12], a[13], R, I);
        if ((wq >> 1) & 1)
            crx_elem<4>(a[14], a[15], R, I);

        // ---- g=1: tgt lane0..3 ; ctrl e, j0, j1, j2 ----
        { float ss = (lane & 1) ? a[17] : -a[17];
          crz_e(a[16], ss, R, I); }
        { float ss = ((lane >> 1) & 1) ? a[19] : -a[19];
          crz_ctrlj<0>(a[18], ss, R, I); }
        { float ss = ((lane >> 2) & 1) ? a[21] : -a[21];
          crz_ctrlj<1>(a[20], ss, R, I); }
        { float ss = ((lane >> 3) & 1) ? a[23] : -a[23];
          crz_ctrlj<2>(a[22], ss, R, I); }
        crx_sh_e(a[24], a[25], R, I);                  // mask 1  (DPP)
        crx_shj_dpp<0, DPP_XOR2>(a[26], a[27], R, I);  // mask 2  (DPP)
        crx_shj_swz4<1>(a[28], a[29], R, I);           // mask 4  (DS)
        crx_shj_dpp<2, DPP_XOR8>(a[30], a[31], R, I);  // mask 8  (DPP)

        // ---- g=2: tgt lane4,lane5,wq0,wq1 ; ctrl lane0..3 (uniform) ----
        crz_g2_fused(a + 32, R, I, lane, wq);
        { bool cb = lane & 1;
          crx_swz16_all(cb ? a[40] : 1.0f, cb ? a[41] : 0.0f, R, I); } // DS
        { bool cb = (lane >> 1) & 1;
          crx_bperm32(cb ? a[42] : 1.0f, cb ? a[43] : 0.0f, R, I, pa); } // DS
        // m=2: cross-wave CRX (tgt wq bit 0), ctrl lane bit 2
        __syncthreads();
        if (act2) {
#pragma unroll
            for (int j = 0; j < 8; ++j) {
                xw2[j]     = R[j];
                xw2[8 + j] = I[j];
            }
        }
        __syncthreads();
        if (act2) {
            float cg = a[44], sg = a[45];
#pragma unroll
            for (int j = 0; j < 8; ++j) {
                f2 br = xr2[j], bi = xr2[8 + j];
                f2 r = R[j], im = I[j];
                R[j] = cg * r + sg * bi;
                I[j] = cg * im - sg * br;
            }
        }
        // m=3: cross-wave CRX (tgt wq bit 1), ctrl lane bit 3
        __syncthreads();
        if (act3) {
#pragma unroll
            for (int j = 0; j < 8; ++j) {
                xw3[j]     = R[j];
                xw3[8 + j] = I[j];
            }
        }
        __syncthreads();
        if (act3) {
            float cg = a[46], sg = a[47];
#pragma unroll
            for (int j = 0; j < 8; ++j) {
                f2 br = xr3[j], bi = xr3[8 + j];
                f2 r = R[j], im = I[j];
                R[j] = cg * r + sg * bi;
                I[j] = cg * im - sg * br;
            }
        }
    }

    // expectation values <Z_w>
    f2 accT = {0.0f, 0.0f}, acc8 = {0.0f, 0.0f};
    f2 acc9 = {0.0f, 0.0f}, acc10 = {0.0f, 0.0f};
#pragma unroll
    for (int j = 0; j < 8; ++j) {
        f2 p = R[j] * R[j] + I[j] * I[j];
        accT += p;
        if (j & 4) acc8 -= p; else acc8 += p;
        if (j & 2) acc9 -= p; else acc9 += p;
        if (j & 1) acc10 -= p; else acc10 += p;
    }
    float T   = accT[0] + accT[1];
    float A11 = accT[0] - accT[1];
    float A8  = acc8[0] + acc8[1];
    float A9  = acc9[0] + acc9[1];
    float A10 = acc10[0] + acc10[1];

    // ---- lane reduction: plain sums + signed captures ----
    float dc0, dc1, dc2, dc3, dc4, dc5;
    float x = T;
    { float u = dppf<DPP_XOR1>(x); dc0 = x - u; x += u; }
    { float u = dppf<DPP_XOR2>(x); dc1 = x - u; x += u; }
    { float u = swz4f(x);          dc2 = x - u; x += u; }
    { float u = dppf<DPP_XOR8>(x); dc3 = x - u; x += u; }
    { float s = psum16(x);         dc4 = 2.0f * x - s; x = s; }
    { float s = psum32(x);         dc5 = 2.0f * x - s; x = s; }
    dc0 += dppf<DPP_XOR2>(dc0);
    dc0 += swz4f(dc0);
    dc0 += dppf<DPP_XOR8>(dc0);
    dc0 = psum16(dc0);  dc0 = psum32(dc0);
    dc1 += swz4f(dc1);
    dc1 += dppf<DPP_XOR8>(dc1);
    dc1 = psum16(dc1);  dc1 = psum32(dc1);
    dc2 += dppf<DPP_XOR8>(dc2);
    dc2 = psum16(dc2);  dc2 = psum32(dc2);
    dc3 = psum16(dc3);  dc3 = psum32(dc3);
    dc4 = psum32(dc4);
    // plain sums for A8..A11
    A8  += dppf<DPP_XOR1>(A8);   A8  += dppf<DPP_XOR2>(A8);
    A8  += swz4f(A8);            A8  += dppf<DPP_XOR8>(A8);
    A8  = psum16(A8);            A8  = psum32(A8);
    A9  += dppf<DPP_XOR1>(A9);   A9  += dppf<DPP_XOR2>(A9);
    A9  += swz4f(A9);            A9  += dppf<DPP_XOR8>(A9);
    A9  = psum16(A9);            A9  = psum32(A9);
    A10 += dppf<DPP_XOR1>(A10);  A10 += dppf<DPP_XOR2>(A10);
    A10 += swz4f(A10);           A10 += dppf<DPP_XOR8>(A10);
    A10 = psum16(A10);           A10 = psum32(A10);
    A11 += dppf<DPP_XOR1>(A11);  A11 += dppf<DPP_XOR2>(A11);
    A11 += swz4f(A11);           A11 += dppf<DPP_XOR8>(A11);
    A11 = psum16(A11);           A11 = psum32(A11);

    // cross-wave combine via LDS (reuse xbuf; barrier protects last exchange)
    __syncthreads();
    if (lane == 0) {
        float* wv = &xbuff[wq * 12];
        wv[0]  = (wq >> 1) ? -x : x;   // qubit 0 <- wq bit 1
        wv[1]  = (wq & 1)  ? -x : x;   // qubit 1 <- wq bit 0
        wv[2]  = dc5;                  // qubit 2 <- lane bit 5
        wv[3]  = dc4;                  // qubit 3 <- lane bit 4
        wv[4]  = dc3;                  // qubit 4 <- lane bit 3
        wv[5]  = dc2;                  // qubit 5 <- lane bit 2
        wv[6]  = dc1;                  // qubit 6 <- lane bit 1
        wv[7]  = dc0;                  // qubit 7 <- lane bit 0
        wv[8]  = A8;
        wv[9]  = A9;
        wv[10] = A10;
        wv[11] = A11;
    }
    __syncthreads();
    if (ts < 12) {
        float z = xbuff[ts] + xbuff[12 + ts] + xbuff[24 + ts] + xbuff[36 + ts];
        outp[ibase + (ts / 3) * 40 + (ts % 3)] = z;
    }
}

__global__ void q4_kernel(const float* __restrict__ inp,
                          const float* __restrict__ cs4,
                          float* __restrict__ outp)
{
    int b = blockIdx.x * blockDim.x + threadIdx.x;
    if (b >= 1024) return;
    float cw[4], sw[4];
#pragma unroll
    for (int j = 0; j < 4; ++j) {
        float x = inp[(b * 4 + j) * 40 + 39];
        __sincosf(0.5f * x, &sw[j], &cw[j]);
    }
    float sr[16], si[16];
#pragma unroll
    for (int k = 0; k < 16; ++k) {
        float v = 1.0f;
#pragma unroll
        for (int j = 0; j < 4; ++j)
            v *= ((k >> (3 - j)) & 1) ? sw[j] : cw[j];
        int ph = __popc(k) & 3;
        sr[k] = (ph == 0) ? v : (ph == 2) ? -v : 0.0f;
        si[k] = (ph == 1) ? -v : (ph == 3) ? v : 0.0f;
    }
#pragma unroll
    for (int l = 0; l < 4; ++l) {
        // RX(theta[4l+w]) on qubit w (bit 3-w)
#pragma unroll
        for (int w = 0; w < 4; ++w) {
            float cg = cs4[2 * (4 * l + w)], sg = cs4[2 * (4 * l + w) + 1];
            const int m = 1 << (3 - w);
#pragma unroll
            for (int k = 0; k < 16; ++k) {
                if (k & m) continue;
                int p2 = k | m;
                float r0 = sr[k], i0 = si[k], r1 = sr[p2], i1 = si[p2];
                sr[k]  = cg * r0 + sg * i1;  si[k]  = cg * i0 - sg * r1;
                sr[p2] = cg * r1 + sg * i0;  si[p2] = cg * i1 - sg * r0;
            }
        }
        // CNOT (0,1),(1,2),(2,3),(3,0)
#pragma unroll
        for (int e = 0; e < 4; ++e) {
            const int cq = e, tq = (e + 1) & 3;
            const int pcb = 1 << (3 - cq), ptb = 1 << (3 - tq);
#pragma unroll
            for (int k = 0; k < 16; ++k) {
                if (!(k & pcb)) continue;
                if (k & ptb) continue;
                int p2 = k | ptb;
                float tr = sr[k], ti = si[k];
                sr[k] = sr[p2]; si[k] = si[p2];
                sr[p2] = tr;    si[p2] = ti;
            }
        }
    }
    float p[16];
#pragma unroll
    for (int k = 0; k < 16; ++k) p[k] = sr[k] * sr[k] + si[k] * si[k];
#pragma unroll
    for (int j = 0; j < 4; ++j) {
        float z = 0.0f;
#pragma unroll
        for (int k = 0; k < 16; ++k)
            z += ((k >> (3 - j)) & 1) ? -p[k] : p[k];
        outp[(b * 4 + j) * 40 + 39] = z;
    }
}

__global__ void prep_kernel(const float* __restrict__ q12,
                            const float* __restrict__ q4,
                            float* __restrict__ cs12,
                            float* __restrict__ cs4)
{
    int idx = blockIdx.x * 256 + threadIdx.x;
    if (idx < 26 * 72) {
        // gate angle = 2*pi*p, half-angle = pi*p
        float s, c;
        sincosf(PI_F * q12[idx], &s, &c);
        cs12[2 * idx]     = c;
        cs12[2 * idx + 1] = s;
    }
    if (idx < 16) {
        float s, c;
        sincosf(0.5f * q4[idx], &s, &c);
        cs4[2 * idx]     = c;
        cs4[2 * idx + 1] = s;
    }
}

__global__ void tmlp_kernel(const float* __restrict__ emb,
                            const float* __restrict__ W,
                            const float* __restrict__ bias,
                            float* __restrict__ t)
{
    __shared__ float se[128];
    int b = blockIdx.x, tid = threadIdx.x;
    float e = emb[b * 128 + tid];
    se[tid] = e / (1.0f + __expf(-e));
    __syncthreads();
    if (tid < 80) {
        float acc = bias[tid];
        for (int k = 0; k < 128; ++k) acc += se[k] * W[k * 80 + tid];
        t[b * 80 + tid] = acc;
    }
}

__global__ void gn0_kernel(const float* __restrict__ h, const float* __restrict__ t,
                           const float* __restrict__ sc, const float* __restrict__ bi,
                           float* __restrict__ outp)
{
    __shared__ float v[160];
    __shared__ float mu[10], rstd[10];
    int b = blockIdx.x, tid = threadIdx.x;
    if (tid < 160) v[tid] = h[b * 160 + tid];
    __syncthreads();
    if (tid < 10) {
        float s1 = 0.0f, s2 = 0.0f;
#pragma unroll
        for (int sp = 0; sp < 4; ++sp)
#pragma unroll
            for (int k = 0; k < 4; ++k) {
                float x = v[sp * 40 + tid * 4 + k];
                s1 += x; s2 += x * x;
            }
        float m = s1 * (1.0f / 16.0f);
        float var = s2 * (1.0f / 16.0f) - m * m;
        mu[tid] = m; rstd[tid] = rsqrtf(var + 1e-6f);
    }
    __syncthreads();
    if (tid < 160) {
        int ch = tid % 40;
        int g = ch >> 2;
        float hn = (v[tid] - mu[g]) * rstd[g] * sc[ch] + bi[ch];
        float scale = t[b * 80 + ch], shift = t[b * 80 + 40 + ch];
        float z = hn * (1.0f + scale) + shift;
        outp[b * 160 + tid] = z / (1.0f + __expf(-z));
    }
}

__global__ void gn1_kernel(const float* __restrict__ h, const float* __restrict__ x,
                           const float* __restrict__ sc, const float* __restrict__ bi,
                           float* __restrict__ outp)
{
    __shared__ float v[160];
    __shared__ float mu[10], rstd[10];
    int b = blockIdx.x, tid = threadIdx.x;
    if (tid < 160) v[tid] = h[b * 160 + tid];
    __syncthreads();
    if (tid < 10) {
        float s1 = 0.0f, s2 = 0.0f;
#pragma unroll
        for (int sp = 0; sp < 4; ++sp)
#pragma unroll
            for (int k = 0; k < 4; ++k) {
                float xx = v[sp * 40 + tid * 4 + k];
                s1 += xx; s2 += xx * xx;
            }
        float m = s1 * (1.0f / 16.0f);
        float var = s2 * (1.0f / 16.0f) - m * m;
        mu[tid] = m; rstd[tid] = rsqrtf(var + 1e-6f);
    }
    __syncthreads();
    if (tid < 160) {
        int ch = tid % 40;
        int g = ch >> 2;
        float hn = (v[tid] - mu[g]) * rstd[g] * sc[ch] + bi[ch];
        float sws = hn / (1.0f + __expf(-hn));
        outp[b * 160 + tid] = x[b * 160 + tid] + sws;
    }
}

extern "C" void kernel_launch(void* const* d_in, const int* in_sizes, int n_in,
                              void* d_out, int out_size, void* d_ws, size_t ws_size,
                              hipStream_t stream)
{
    const float* x    = (const float*)d_in[0];
    const float* temb = (const float*)d_in[1];
    const float* q12  = (const float*)d_in[2];
    const float* q4   = (const float*)d_in[3];
    const float* gn0s = (const float*)d_in[4];
    const float* gn0b = (const float*)d_in[5];
    const float* gn1s = (const float*)d_in[6];
    const float* gn1b = (const float*)d_in[7];
    const float* tw   = (const float*)d_in[8];
    const float* tb   = (const float*)d_in[9];
    float* out = (float*)d_out;

    float* ws   = (float*)d_ws;
    float* cs12 = ws;               // 26*72*2   = 3744
    float* cs4  = cs12 + 3744;      // 32
    float* tbuf = cs4 + 32;         // 1024*80   = 81920
    float* A    = tbuf + 81920;     // 1024*160  = 163840 (raw qpass out)
    float* Bf   = A + 163840;       // 1024*160  = 163840 (gn0 out / qpass2 in)

    prep_kernel<<<8, 256, 0, stream>>>(q12, q4, cs12, cs4);
    tmlp_kernel<<<1024, 128, 0, stream>>>(temb, tw, tb, tbuf);

    // pass 1  (13312 WGs x 1 sim x 4 waves)
    qpass12_kernel<<<13312, 256, 0, stream>>>(x, cs12, A);
    q4_kernel<<<16, 64, 0, stream>>>(x, cs4, A);
    gn0_kernel<<<1024, 160, 0, stream>>>(A, tbuf, gn0s, gn0b, Bf);

    // pass 2
    qpass12_kernel<<<13312, 256, 0, stream>>>(Bf, cs12 + 13 * 144, A);
    q4_kernel<<<16, 64, 0, stream>>>(Bf, cs4, A);
    gn1_kernel<<<1024, 160, 0, stream>>>(A, x, gn1s, gn1b, out);
}

// Round 16
// 524.497 us; speedup vs baseline: 1.4823x; 1.4823x over previous
//
#include <hip/hip_runtime.h>
#include <math.h>

// ---------------------------------------------------------------------------
// QFullResnetBlock: two quantum passes (13x 12-qubit sims + 1x 4-qubit sim per
// batch elem) + groupnorm/time-FiLM/swish glue + residual.
//
// 12-qubit sim: FOUR waves per sim (one 256-thread WG = 1 sim), 16 amps per
// thread as packed-FP32 pairs: f2 R[8], I[8] = 16 VGPR state.
// Amplitude amp (12 bits) = (wq << 10) | (lane << 4) | (j << 1) | e :
//   bit  0     = e    (element of the f2)
//   bits 1..3  = j    (8 register pairs)
//   bits 4..9  = lane (lane bit L = amp bit 4+L)
//   bits 10,11 = wq   (wave within sim; 2 masked LDS exchanges per layer)
// Qubit w lives at amp bit (11-w).
//
// LAUNCH-BOUNDS MODEL (R14/R15 A/B, now fully characterized):
//   - SPI schedules residency to the DECLARED min-waves (2nd arg):
//     min=4 -> 54% occupancy; min=8 -> 86%.
//   - allocator VGPR bucket ~= 256/min_waves: min=4 -> 64; min=8 -> 32.
//   - spill iff demand > bucket (R15: 44 > 32 -> 1.1 GB scratch, 777us).
// Demand = 44 -> min_waves = 5 is the max no-spill point (bucket ~48-51);
// LDS 5*17408 = 87KB <= 160KB. __launch_bounds__(256, 5) this round.
//
// Cross-lane op map: mask1->DPP 0xB1, mask2->DPP 0x4E, mask4->swz 0x101F,
// mask8->DPP row_ror:8, mask16->swz 0x401F, mask32->ds_bpermute.
//
// R10 LESSON (kept): inline-asm with two "+v" operands initialized from the
// SAME value can coalesce onto one physical register -> permlane_swap
// degenerates. psum16/psum32 use "=&v" early-clobber + explicit movs.
//
// R13 LESSON (kept): doubling LDS (fused exchange) cut occupancy -> net
// regression; occupancy beats barrier count at this operating point.
//
// Gate pattern per layer l, group g, m=0..3 (amp-bit positions):
//   target bit pt = 4g+m, control bit pc = (4g+8+m)%12
//   g=0: tgt e,j0,j1,j2 (local);    ctrl lane4,lane5,wq0,wq1 (uniform folds)
//   g=1: tgt lane0..3 (exchanges);  ctrl e,j0,j1,j2 (element/reg masks)
//   g=2: tgt lane4,lane5 (swz16/bperm32) + wq0,wq1 (LDS); ctrl lane0..3
// ---------------------------------------------------------------------------

#define PI_F 3.14159265358979323846f

#define DPP_XOR1 0xB1
#define DPP_XOR2 0x4E
#define DPP_XOR8 0x128

typedef float f2 __attribute__((ext_vector_type(2)));

template<int CTRL>
__device__ __forceinline__ float dppf(float x)
{
    return __int_as_float(__builtin_amdgcn_update_dpp(
        __float_as_int(x), __float_as_int(x), CTRL, 0xF, 0xF, false));
}

template<int CTRL>
__device__ __forceinline__ f2 dpp2v(f2 v)
{
    f2 r;
    r[0] = dppf<CTRL>(v[0]);
    r[1] = dppf<CTRL>(v[1]);
    return r;
}

__device__ __forceinline__ float swz4f(float x)
{
    // ds_swizzle BitMode xor_mask=4: offset = (4<<10) | 0x1F
    return __int_as_float(__builtin_amdgcn_ds_swizzle(__float_as_int(x), 0x101F));
}

__device__ __forceinline__ f2 swz4v(f2 v)
{
    f2 r;
    r[0] = swz4f(v[0]);
    r[1] = swz4f(v[1]);
    return r;
}

__device__ __forceinline__ float swz16f(float x)
{
    // ds_swizzle BitMode xor_mask=16: offset = (16<<10) | 0x1F
    return __int_as_float(__builtin_amdgcn_ds_swizzle(__float_as_int(x), 0x401F));
}

__device__ __forceinline__ f2 swz16v(f2 v)
{
    f2 r;
    r[0] = swz16f(v[0]);
    r[1] = swz16f(v[1]);
    return r;
}

// x + shfl_xor(x,16): one permlane16_swap over two GUARANTEED-DISTINCT regs
// (early-clobber outputs; R10 aliasing lesson). Orientation-independent.
__device__ __forceinline__ float psum16(float x)
{
    float c, d;
    asm("v_mov_b32 %0, %2\n\t"
        "v_mov_b32 %1, %2\n\t"
        "v_permlane16_swap_b32 %0, %1"
        : "=&v"(c), "=&v"(d)
        : "v"(x));
    return c + d;
}

__device__ __forceinline__ float psum32(float x)
{
    float c, d;
    asm("v_mov_b32 %0, %2\n\t"
        "v_mov_b32 %1, %2\n\t"
        "v_permlane32_swap_b32 %0, %1"
        : "=&v"(c), "=&v"(d)
        : "v"(x));
    return c + d;
}

// ---- g=0 ------------------------------------------------------------------
// Fused CRZ group: 4 diagonal gates, ctrl lane4/lane5/wq0/wq1 (thread-uniform
// folds), target amp bits 0..3 = (j<<1)|e. M[15-t] = conj(M[t]).
// Multiplier built once as packed f2 (MrV/MiV over t=0..7); conj half applied
// via op_sel swap with signs folded into the FMA pattern.
__device__ __forceinline__ void crz_g0_fused(const float* a, f2* R, f2* I,
                                             int lane, int wq)
{
    float gr[4], gi[4];
#pragma unroll
    for (int m = 0; m < 4; ++m) {
        bool cb;
        if      (m == 0) cb = (lane >> 4) & 1;
        else if (m == 1) cb = (lane >> 5) & 1;
        else if (m == 2) cb = wq & 1;
        else             cb = (wq >> 1) & 1;
        gr[m] = cb ? a[2 * m]     : 1.0f;
        gi[m] = cb ? a[2 * m + 1] : 0.0f;
    }
    float u0 = gr[1] * gr[0], v0 = gi[1] * gi[0];
    float w0 = gr[1] * gi[0], z0 = gi[1] * gr[0];
    float p01r[2] = { u0 - v0, u0 + v0 };
    float p01i[2] = { -(w0 + z0), w0 - z0 };
    float u1 = gr[3] * gr[2], v1 = gi[3] * gi[2];
    float w1 = gr[3] * gi[2], z1 = gi[3] * gr[2];
    float p23r[2] = { u1 - v1, u1 + v1 };
    float p23i[2] = { -(w1 + z1), w1 - z1 };

    // table: MrV[p] = {M[2p].r, M[2p+1].r}, MiV[p] = {M[2p].i, M[2p+1].i}
    f2 MrV[4], MiV[4];
#pragma unroll
    for (int p = 0; p < 4; ++p) {
#pragma unroll
        for (int e = 0; e < 2; ++e) {
            const int t = 2 * p + e;
            const int t10 = t & 3, t2 = (t >> 2) & 1;
            float br = (t10 == 0 || t10 == 3) ? p01r[0] : p01r[1];
            float bi = (t10 == 0) ? p01i[0] : (t10 == 1) ? p01i[1]
                     : (t10 == 2) ? -p01i[1] : -p01i[0];
            MrV[p][e] = p23r[t2] * br - p23i[t2] * bi;
            MiV[p][e] = p23r[t2] * bi + p23i[t2] * br;
        }
    }
    // j < 4: direct
#pragma unroll
    for (int j = 0; j < 4; ++j) {
        f2 mr = MrV[j], mi = MiV[j];
        f2 r = R[j], im = I[j];
        R[j] = mr * r - mi * im;
        I[j] = mr * im + mi * r;
    }
    // j >= 4: conj-mirror -> R' = swap(Mr)*r + swap(Mi)*im ;
    //                        I' = swap(Mr)*im - swap(Mi)*r
#pragma unroll
    for (int j = 4; j < 8; ++j) {
        f2 mr = __builtin_shufflevector(MrV[7 - j], MrV[7 - j], 1, 0);
        f2 mi = __builtin_shufflevector(MiV[7 - j], MiV[7 - j], 1, 0);
        f2 r = R[j], im = I[j];
        R[j] = mr * r + mi * im;
        I[j] = mr * im - mi * r;
    }
}

// CRX within the pair (target = e), uniform folded coeff
__device__ __forceinline__ void crx_pair(float cg, float sg, f2* R, f2* I)
{
#pragma unroll
    for (int j = 0; j < 8; ++j) {
        f2 r = R[j], im = I[j];
        f2 rs = __builtin_shufflevector(r, r, 1, 0);
        f2 is = __builtin_shufflevector(im, im, 1, 0);
        R[j] = cg * r + sg * is;
        I[j] = cg * im - sg * rs;
    }
}

// CRX between registers j and j|M (target = j bit), uniform coeff
template<int M>
__device__ __forceinline__ void crx_elem(float cg, float sg, f2* R, f2* I)
{
#pragma unroll
    for (int j = 0; j < 8; ++j) {
        if (j & M) continue;
        const int p = j | M;
        f2 r0 = R[j], i0 = I[j], r1 = R[p], i1 = I[p];
        R[j] = cg * r0 + sg * i1;  I[j] = cg * i0 - sg * r1;
        R[p] = cg * r1 + sg * i0;  I[p] = cg * i1 - sg * r0;
    }
}

// ---- g=1 ------------------------------------------------------------------
// CRZ, ctrl = e (hi element only), sign by lane bit 0
__device__ __forceinline__ void crz_e(float cg, float ss, f2* R, f2* I)
{
    const f2 mrv = {1.0f, cg};
    const f2 miv = {0.0f, ss};
#pragma unroll
    for (int j = 0; j < 8; ++j) {
        f2 r = R[j], im = I[j];
        R[j] = mrv * r - miv * im;
        I[j] = mrv * im + miv * r;
    }
}

// CRZ, ctrl = j bit CB, thread-uniform (cg, ss)
template<int CB>
__device__ __forceinline__ void crz_ctrlj(float cg, float ss, f2* R, f2* I)
{
#pragma unroll
    for (int j = 0; j < 8; ++j) {
        if (!((j >> CB) & 1)) continue;
        f2 r = R[j], im = I[j];
        R[j] = cg * r - ss * im;
        I[j] = cg * im + ss * r;
    }
}

// CRX, ctrl = e (hi element), target = lane bit 0 (DPP xor1, VALU pipe)
__device__ __forceinline__ void crx_sh_e(float cg, float sg, f2* R, f2* I)
{
    const f2 cgv = {1.0f, cg};
    const f2 sgv = {0.0f, sg};
#pragma unroll
    for (int j = 0; j < 8; ++j) {
        f2 br = dpp2v<DPP_XOR1>(R[j]);
        f2 bi = dpp2v<DPP_XOR1>(I[j]);
        f2 r = R[j], im = I[j];
        R[j] = cgv * r + sgv * bi;
        I[j] = cgv * im - sgv * br;
    }
}

// CRX, ctrl = j bit CB, target lane exchange via DPP (VALU pipe)
template<int CB, int CTRL>
__device__ __forceinline__ void crx_shj_dpp(float cg, float sg, f2* R, f2* I)
{
#pragma unroll
    for (int j = 0; j < 8; ++j) {
        if (!((j >> CB) & 1)) continue;
        f2 br = dpp2v<CTRL>(R[j]);
        f2 bi = dpp2v<CTRL>(I[j]);
        f2 r = R[j], im = I[j];
        R[j] = cg * r + sg * bi;
        I[j] = cg * im - sg * br;
    }
}

// CRX, ctrl = j bit CB, target = lane bit 2 (mask 4: ds_swizzle, DS pipe)
template<int CB>
__device__ __forceinline__ void crx_shj_swz4(float cg, float sg, f2* R, f2* I)
{
#pragma unroll
    for (int j = 0; j < 8; ++j) {
        if (!((j >> CB) & 1)) continue;
        f2 br = swz4v(R[j]);
        f2 bi = swz4v(I[j]);
        f2 r = R[j], im = I[j];
        R[j] = cg * r + sg * bi;
        I[j] = cg * im - sg * br;
    }
}

// ---- g=2 ------------------------------------------------------------------
// Fused CRZ group: all 4 gates thread-uniform ctrl + sign -> ONE multiplier.
__device__ __forceinline__ void crz_g2_fused(const float* a, f2* R, f2* I,
                                             int lane, int wq)
{
    float s0 = ((lane >> 4) & 1) ? a[1] : -a[1];
    bool  c0 = lane & 1;
    float f0r = c0 ? a[0] : 1.0f, f0i = c0 ? s0 : 0.0f;
    float s1 = ((lane >> 5) & 1) ? a[3] : -a[3];
    bool  c1 = (lane >> 1) & 1;
    float f1r = c1 ? a[2] : 1.0f, f1i = c1 ? s1 : 0.0f;
    float s2 = (wq & 1) ? a[5] : -a[5];
    bool  c2 = (lane >> 2) & 1;
    float f2r = c2 ? a[4] : 1.0f, f2i = c2 ? s2 : 0.0f;
    float s3 = ((wq >> 1) & 1) ? a[7] : -a[7];
    bool  c3 = (lane >> 3) & 1;
    float f3r = c3 ? a[6] : 1.0f, f3i = c3 ? s3 : 0.0f;
    float t01r = f0r * f1r - f0i * f1i, t01i = f0r * f1i + f0i * f1r;
    float t23r = f2r * f3r - f2i * f3i, t23i = f2r * f3i + f2i * f3r;
    float Pr = t01r * t23r - t01i * t23i;
    float Pi = t01r * t23i + t01i * t23r;
#pragma unroll
    for (int j = 0; j < 8; ++j) {
        f2 r = R[j], im = I[j];
        R[j] = Pr * r - Pi * im;
        I[j] = Pr * im + Pi * r;
    }
}

// CRX, uniform folded ctrl, target = lane bit 4 via ds_swizzle xor16 (DS)
__device__ __forceinline__ void crx_swz16_all(float cg, float sg, f2* R, f2* I)
{
#pragma unroll
    for (int j = 0; j < 8; ++j) {
        f2 br = swz16v(R[j]);
        f2 bi = swz16v(I[j]);
        f2 r = R[j], im = I[j];
        R[j] = cg * r + sg * bi;
        I[j] = cg * im - sg * br;
    }
}

// CRX, uniform folded ctrl, target = lane bit 5 via ds_bpermute (DS pipe;
// wave-wide lane indexing on CDNA). pa = (lane ^ 32) << 2.
__device__ __forceinline__ void crx_bperm32(float cg, float sg, f2* R, f2* I,
                                            int pa)
{
#pragma unroll
    for (int j = 0; j < 8; ++j) {
        f2 br, bi;
        br[0] = __int_as_float(__builtin_amdgcn_ds_bpermute(pa, __float_as_int(R[j][0])));
        br[1] = __int_as_float(__builtin_amdgcn_ds_bpermute(pa, __float_as_int(R[j][1])));
        bi[0] = __int_as_float(__builtin_amdgcn_ds_bpermute(pa, __float_as_int(I[j][0])));
        bi[1] = __int_as_float(__builtin_amdgcn_ds_bpermute(pa, __float_as_int(I[j][1])));
        f2 r = R[j], im = I[j];
        R[j] = cg * r + sg * bi;
        I[j] = cg * im - sg * br;
    }
}

__global__ void __launch_bounds__(256, 5)
qpass12_kernel(const float* __restrict__ inp, const float* __restrict__ cs,
               float* __restrict__ outp)
{
    // exchange buffer: [wq 0..3][row 0..31] x 17 f2 (16 data + 1 pad).
    // 4*32*17 f2 = 17408 B -> 5 WGs/CU fit (87040 <= 163840).
    __shared__ f2 xbufv[4 * 32 * 17];
    float* xbuff = reinterpret_cast<float*>(xbufv);
    const int ts   = threadIdx.x;
    const int wq   = ts >> 6;             // amp bits 10 (wq&1), 11 (wq>>1)
    const int lane = ts & 63;             // amp bits 4..9
    const int sim  = blockIdx.x;
    const int ci = sim % 13;
    const int b  = sim / 13;
    const float* csc = cs + ci * 144;     // 72 gates * (cos,sin)
    const int ibase = b * 160 + ci * 3;   // (B,2,2,40) flat; sp stride 40

    // data angles: qubit w <- inp[b, w/3, (w%3)+3*ci]
    float cw[12], sw[12];
#pragma unroll
    for (int w = 0; w < 12; ++w) {
        float x = inp[ibase + (w / 3) * 40 + (w % 3)];
        __sincosf(0.5f * x, &sw[w], &cw[w]);
    }

    // product-state init: qubit w at amp bit 11-w.
    float pref = ((wq >> 1) ? sw[0] : cw[0]) * ((wq & 1) ? sw[1] : cw[1]);
#pragma unroll
    for (int w = 2; w < 8; ++w)
        pref *= ((lane >> (7 - w)) & 1) ? sw[w] : cw[w];

    const int pl = (__popc(lane) + __popc(wq)) & 3;
    float oa = (pl == 0) ? 1.0f : (pl == 2) ? -1.0f : 0.0f;
    float ob = (pl == 1) ? -1.0f : (pl == 3) ? 1.0f : 0.0f;

    f2 R[8], I[8];
#pragma unroll
    for (int j = 0; j < 8; ++j) {
        float base = pref * ((j & 4) ? sw[8] : cw[8]) *
                     ((j & 2) ? sw[9] : cw[9]) * ((j & 1) ? sw[10] : cw[10]);
        f2 v2 = { base * cw[11], base * sw[11] };
        const int q0 = __popc(j) & 3;
        const int q1 = (q0 + 1) & 3;
        const float c0l = (q0 == 0) ? oa : (q0 == 1) ? ob : (q0 == 2) ? -oa : -ob;
        const float c1l = (q0 == 0) ? ob : (q0 == 1) ? -oa : (q0 == 2) ? -ob : oa;
        const float c0h = (q1 == 0) ? oa : (q1 == 1) ? ob : (q1 == 2) ? -oa : -ob;
        const float c1h = (q1 == 0) ? ob : (q1 == 1) ? -oa : (q1 == 2) ? -ob : oa;
        R[j] = f2{ v2[0] * c0l, v2[1] * c0h };
        I[j] = f2{ v2[0] * c1l, v2[1] * c1h };
    }

    // cross-wave exchange addressing
    const bool act2 = (lane >> 2) & 1;
    const bool act3 = (lane >> 3) & 1;
    const int ai2 = ((lane >> 3) << 2) | (lane & 3);
    const int ai3 = ((lane >> 4) << 3) | (lane & 7);
    const int pa  = ((lane ^ 32) << 2);   // bpermute partner byte addr
    f2* xw2 = &xbufv[(wq * 32 + ai2) * 17];
    f2* xr2 = &xbufv[((wq ^ 1) * 32 + ai2) * 17];
    f2* xw3 = &xbufv[(wq * 32 + ai3) * 17];
    f2* xr3 = &xbufv[((wq ^ 2) * 32 + ai3) * 17];

#pragma unroll 1
    for (int l = 0; l < 3; ++l) {
        const float* a = csc + l * 48;

        // ---- g=0: tgt e,j0,j1,j2 ; ctrl lane4,lane5,wq0,wq1 ----
        crz_g0_fused(a, R, I, lane, wq);
        { bool cb = (lane >> 4) & 1;
          crx_pair(cb ? a[ 8] : 1.0f, cb ? a[ 9] : 0.0f, R, I); }
        { bool cb = (lane >> 5) & 1;
          crx_elem<1>(cb ? a[10] : 1.0f, cb ? a[11] : 0.0f, R, I); }
        // wq-controlled: WAVE-UNIFORM skip (identity when ctrl clear)
        if (wq & 1)
            crx_elem<2>(a[12], a[13], R, I);
        if ((wq >> 1) & 1)
            crx_elem<4>(a[14], a[15], R, I);

        // ---- g=1: tgt lane0..3 ; ctrl e, j0, j1, j2 ----
        { float ss = (lane & 1) ? a[17] : -a[17];
          crz_e(a[16], ss, R, I); }
        { float ss = ((lane >> 1) & 1) ? a[19] : -a[19];
          crz_ctrlj<0>(a[18], ss, R, I); }
        { float ss = ((lane >> 2) & 1) ? a[21] : -a[21];
          crz_ctrlj<1>(a[20], ss, R, I); }
        { float ss = ((lane >> 3) & 1) ? a[23] : -a[23];
          crz_ctrlj<2>(a[22], ss, R, I); }
        crx_sh_e(a[24], a[25], R, I);                  // mask 1  (DPP)
        crx_shj_dpp<0, DPP_XOR2>(a[26], a[27], R, I);  // mask 2  (DPP)
        crx_shj_swz4<1>(a[28], a[29], R, I);           // mask 4  (DS)
        crx_shj_dpp<2, DPP_XOR8>(a[30], a[31], R, I);  // mask 8  (DPP)

        // ---- g=2: tgt lane4,lane5,wq0,wq1 ; ctrl lane0..3 (uniform) ----
        crz_g2_fused(a + 32, R, I, lane, wq);
        { bool cb = lane & 1;
          crx_swz16_all(cb ? a[40] : 1.0f, cb ? a[41] : 0.0f, R, I); } // DS
        { bool cb = (lane >> 1) & 1;
          crx_bperm32(cb ? a[42] : 1.0f, cb ? a[43] : 0.0f, R, I, pa); } // DS
        // m=2: cross-wave CRX (tgt wq bit 0), ctrl lane bit 2
        __syncthreads();
        if (act2) {
#pragma unroll
            for (int j = 0; j < 8; ++j) {
                xw2[j]     = R[j];
                xw2[8 + j] = I[j];
            }
        }
        __syncthreads();
        if (act2) {
            float cg = a[44], sg = a[45];
#pragma unroll
            for (int j = 0; j < 8; ++j) {
                f2 br = xr2[j], bi = xr2[8 + j];
                f2 r = R[j], im = I[j];
                R[j] = cg * r + sg * bi;
                I[j] = cg * im - sg * br;
            }
        }
        // m=3: cross-wave CRX (tgt wq bit 1), ctrl lane bit 3
        __syncthreads();
        if (act3) {
#pragma unroll
            for (int j = 0; j < 8; ++j) {
                xw3[j]     = R[j];
                xw3[8 + j] = I[j];
            }
        }
        __syncthreads();
        if (act3) {
            float cg = a[46], sg = a[47];
#pragma unroll
            for (int j = 0; j < 8; ++j) {
                f2 br = xr3[j], bi = xr3[8 + j];
                f2 r = R[j], im = I[j];
                R[j] = cg * r + sg * bi;
                I[j] = cg * im - sg * br;
            }
        }
    }

    // expectation values <Z_w>
    f2 accT = {0.0f, 0.0f}, acc8 = {0.0f, 0.0f};
    f2 acc9 = {0.0f, 0.0f}, acc10 = {0.0f, 0.0f};
#pragma unroll
    for (int j = 0; j < 8; ++j) {
        f2 p = R[j] * R[j] + I[j] * I[j];
        accT += p;
        if (j & 4) acc8 -= p; else acc8 += p;
        if (j & 2) acc9 -= p; else acc9 += p;
        if (j & 1) acc10 -= p; else acc10 += p;
    }
    float T   = accT[0] + accT[1];
    float A11 = accT[0] - accT[1];
    float A8  = acc8[0] + acc8[1];
    float A9  = acc9[0] + acc9[1];
    float A10 = acc10[0] + acc10[1];

    // ---- lane reduction: plain sums + signed captures ----
    float dc0, dc1, dc2, dc3, dc4, dc5;
    float x = T;
    { float u = dppf<DPP_XOR1>(x); dc0 = x - u; x += u; }
    { float u = dppf<DPP_XOR2>(x); dc1 = x - u; x += u; }
    { float u = swz4f(x);          dc2 = x - u; x += u; }
    { float u = dppf<DPP_XOR8>(x); dc3 = x - u; x += u; }
    { float s = psum16(x);         dc4 = 2.0f * x - s; x = s; }
    { float s = psum32(x);         dc5 = 2.0f * x - s; x = s; }
    dc0 += dppf<DPP_XOR2>(dc0);
    dc0 += swz4f(dc0);
    dc0 += dppf<DPP_XOR8>(dc0);
    dc0 = psum16(dc0);  dc0 = psum32(dc0);
    dc1 += swz4f(dc1);
    dc1 += dppf<DPP_XOR8>(dc1);
    dc1 = psum16(dc1);  dc1 = psum32(dc1);
    dc2 += dppf<DPP_XOR8>(dc2);
    dc2 = psum16(dc2);  dc2 = psum32(dc2);
    dc3 = psum16(dc3);  dc3 = psum32(dc3);
    dc4 = psum32(dc4);
    // plain sums for A8..A11
    A8  += dppf<DPP_XOR1>(A8);   A8  += dppf<DPP_XOR2>(A8);
    A8  += swz4f(A8);            A8  += dppf<DPP_XOR8>(A8);
    A8  = psum16(A8);            A8  = psum32(A8);
    A9  += dppf<DPP_XOR1>(A9);   A9  += dppf<DPP_XOR2>(A9);
    A9  += swz4f(A9);            A9  += dppf<DPP_XOR8>(A9);
    A9  = psum16(A9);            A9  = psum32(A9);
    A10 += dppf<DPP_XOR1>(A10);  A10 += dppf<DPP_XOR2>(A10);
    A10 += swz4f(A10);           A10 += dppf<DPP_XOR8>(A10);
    A10 = psum16(A10);           A10 = psum32(A10);
    A11 += dppf<DPP_XOR1>(A11);  A11 += dppf<DPP_XOR2>(A11);
    A11 += swz4f(A11);           A11 += dppf<DPP_XOR8>(A11);
    A11 = psum16(A11);           A11 = psum32(A11);

    // cross-wave combine via LDS (reuse xbuf; barrier protects last exchange)
    __syncthreads();
    if (lane == 0) {
        float* wv = &xbuff[wq * 12];
        wv[0]  = (wq >> 1) ? -x : x;   // qubit 0 <- wq bit 1
        wv[1]  = (wq & 1)  ? -x : x;   // qubit 1 <- wq bit 0
        wv[2]  = dc5;                  // qubit 2 <- lane bit 5
        wv[3]  = dc4;                  // qubit 3 <- lane bit 4
        wv[4]  = dc3;                  // qubit 4 <- lane bit 3
        wv[5]  = dc2;                  // qubit 5 <- lane bit 2
        wv[6]  = dc1;                  // qubit 6 <- lane bit 1
        wv[7]  = dc0;                  // qubit 7 <- lane bit 0
        wv[8]  = A8;
        wv[9]  = A9;
        wv[10] = A10;
        wv[11] = A11;
    }
    __syncthreads();
    if (ts < 12) {
        float z = xbuff[ts] + xbuff[12 + ts] + xbuff[24 + ts] + xbuff[36 + ts];
        outp[ibase + (ts / 3) * 40 + (ts % 3)] = z;
    }
}

__global__ void q4_kernel(const float* __restrict__ inp,
                          const float* __restrict__ cs4,
                          float* __restrict__ outp)
{
    int b = blockIdx.x * blockDim.x + threadIdx.x;
    if (b >= 1024) return;
    float cw[4], sw[4];
#pragma unroll
    for (int j = 0; j < 4; ++j) {
        float x = inp[(b * 4 + j) * 40 + 39];
        __sincosf(0.5f * x, &sw[j], &cw[j]);
    }
    float sr[16], si[16];
#pragma unroll
    for (int k = 0; k < 16; ++k) {
        float v = 1.0f;
#pragma unroll
        for (int j = 0; j < 4; ++j)
            v *= ((k >> (3 - j)) & 1) ? sw[j] : cw[j];
        int ph = __popc(k) & 3;
        sr[k] = (ph == 0) ? v : (ph == 2) ? -v : 0.0f;
        si[k] = (ph == 1) ? -v : (ph == 3) ? v : 0.0f;
    }
#pragma unroll
    for (int l = 0; l < 4; ++l) {
        // RX(theta[4l+w]) on qubit w (bit 3-w)
#pragma unroll
        for (int w = 0; w < 4; ++w) {
            float cg = cs4[2 * (4 * l + w)], sg = cs4[2 * (4 * l + w) + 1];
            const int m = 1 << (3 - w);
#pragma unroll
            for (int k = 0; k < 16; ++k) {
                if (k & m) continue;
                int p2 = k | m;
                float r0 = sr[k], i0 = si[k], r1 = sr[p2], i1 = si[p2];
                sr[k]  = cg * r0 + sg * i1;  si[k]  = cg * i0 - sg * r1;
                sr[p2] = cg * r1 + sg * i0;  si[p2] = cg * i1 - sg * r0;
            }
        }
        // CNOT (0,1),(1,2),(2,3),(3,0)
#pragma unroll
        for (int e = 0; e < 4; ++e) {
            const int cq = e, tq = (e + 1) & 3;
            const int pcb = 1 << (3 - cq), ptb = 1 << (3 - tq);
#pragma unroll
            for (int k = 0; k < 16; ++k) {
                if (!(k & pcb)) continue;
                if (k & ptb) continue;
                int p2 = k | ptb;
                float tr = sr[k], ti = si[k];
                sr[k] = sr[p2]; si[k] = si[p2];
                sr[p2] = tr;    si[p2] = ti;
            }
        }
    }
    float p[16];
#pragma unroll
    for (int k = 0; k < 16; ++k) p[k] = sr[k] * sr[k] + si[k] * si[k];
#pragma unroll
    for (int j = 0; j < 4; ++j) {
        float z = 0.0f;
#pragma unroll
        for (int k = 0; k < 16; ++k)
            z += ((k >> (3 - j)) & 1) ? -p[k] : p[k];
        outp[(b * 4 + j) * 40 + 39] = z;
    }
}

__global__ void prep_kernel(const float* __restrict__ q12,
                            const float* __restrict__ q4,
                            float* __restrict__ cs12,
                            float* __restrict__ cs4)
{
    int idx = blockIdx.x * 256 + threadIdx.x;
    if (idx < 26 * 72) {
        // gate angle = 2*pi*p, half-angle = pi*p
        float s, c;
        sincosf(PI_F * q12[idx], &s, &c);
        cs12[2 * idx]     = c;
        cs12[2 * idx + 1] = s;
    }
    if (idx < 16) {
        float s, c;
        sincosf(0.5f * q4[idx], &s, &c);
        cs4[2 * idx]     = c;
        cs4[2 * idx + 1] = s;
    }
}

__global__ void tmlp_kernel(const float* __restrict__ emb,
                            const float* __restrict__ W,
                            const float* __restrict__ bias,
                            float* __restrict__ t)
{
    __shared__ float se[128];
    int b = blockIdx.x, tid = threadIdx.x;
    float e = emb[b * 128 + tid];
    se[tid] = e / (1.0f + __expf(-e));
    __syncthreads();
    if (tid < 80) {
        float acc = bias[tid];
        for (int k = 0; k < 128; ++k) acc += se[k] * W[k * 80 + tid];
        t[b * 80 + tid] = acc;
    }
}

__global__ void gn0_kernel(const float* __restrict__ h, const float* __restrict__ t,
                           const float* __restrict__ sc, const float* __restrict__ bi,
                           float* __restrict__ outp)
{
    __shared__ float v[160];
    __shared__ float mu[10], rstd[10];
    int b = blockIdx.x, tid = threadIdx.x;
    if (tid < 160) v[tid] = h[b * 160 + tid];
    __syncthreads();
    if (tid < 10) {
        float s1 = 0.0f, s2 = 0.0f;
#pragma unroll
        for (int sp = 0; sp < 4; ++sp)
#pragma unroll
            for (int k = 0; k < 4; ++k) {
                float x = v[sp * 40 + tid * 4 + k];
                s1 += x; s2 += x * x;
            }
        float m = s1 * (1.0f / 16.0f);
        float var = s2 * (1.0f / 16.0f) - m * m;
        mu[tid] = m; rstd[tid] = rsqrtf(var + 1e-6f);
    }
    __syncthreads();
    if (tid < 160) {
        int ch = tid % 40;
        int g = ch >> 2;
        float hn = (v[tid] - mu[g]) * rstd[g] * sc[ch] + bi[ch];
        float scale = t[b * 80 + ch], shift = t[b * 80 + 40 + ch];
        float z = hn * (1.0f + scale) + shift;
        outp[b * 160 + tid] = z / (1.0f + __expf(-z));
    }
}

__global__ void gn1_kernel(const float* __restrict__ h, const float* __restrict__ x,
                           const float* __restrict__ sc, const float* __restrict__ bi,
                           float* __restrict__ outp)
{
    __shared__ float v[160];
    __shared__ float mu[10], rstd[10];
    int b = blockIdx.x, tid = threadIdx.x;
    if (tid < 160) v[tid] = h[b * 160 + tid];
    __syncthreads();
    if (tid < 10) {
        float s1 = 0.0f, s2 = 0.0f;
#pragma unroll
        for (int sp = 0; sp < 4; ++sp)
#pragma unroll
            for (int k = 0; k < 4; ++k) {
                float xx = v[sp * 40 + tid * 4 + k];
                s1 += xx; s2 += xx * xx;
            }
        float m = s1 * (1.0f / 16.0f);
        float var = s2 * (1.0f / 16.0f) - m * m;
        mu[tid] = m; rstd[tid] = rsqrtf(var + 1e-6f);
    }
    __syncthreads();
    if (tid < 160) {
        int ch = tid % 40;
        int g = ch >> 2;
        float hn = (v[tid] - mu[g]) * rstd[g] * sc[ch] + bi[ch];
        float sws = hn / (1.0f + __expf(-hn));
        outp[b * 160 + tid] = x[b * 160 + tid] + sws;
    }
}

extern "C" void kernel_launch(void* const* d_in, const int* in_sizes, int n_in,
                              void* d_out, int out_size, void* d_ws, size_t ws_size,
                              hipStream_t stream)
{
    const float* x    = (const float*)d_in[0];
    const float* temb = (const float*)d_in[1];
    const float* q12  = (const float*)d_in[2];
    const float* q4   = (const float*)d_in[3];
    const float* gn0s = (const float*)d_in[4];
    const float* gn0b = (const float*)d_in[5];
    const float* gn1s = (const float*)d_in[6];
    const float* gn1b = (const float*)d_in[7];
    const float* tw   = (const float*)d_in[8];
    const float* tb   = (const float*)d_in[9];
    float* out = (float*)d_out;

    float* ws   = (float*)d_ws;
    float* cs12 = ws;               // 26*72*2   = 3744
    float* cs4  = cs12 + 3744;      // 32
    float* tbuf = cs4 + 32;         // 1024*80   = 81920
    float* A    = tbuf + 81920;     // 1024*160  = 163840 (raw qpass out)
    float* Bf   = A + 163840;       // 1024*160  = 163840 (gn0 out / qpass2 in)

    prep_kernel<<<8, 256, 0, stream>>>(q12, q4, cs12, cs4);
    tmlp_kernel<<<1024, 128, 0, stream>>>(temb, tw, tb, tbuf);

    // pass 1  (13312 WGs x 1 sim x 4 waves)
    qpass12_kernel<<<13312, 256, 0, stream>>>(x, cs12, A);
    q4_kernel<<<16, 64, 0, stream>>>(x, cs4, A);
    gn0_kernel<<<1024, 160, 0, stream>>>(A, tbuf, gn0s, gn0b, Bf);

    // pass 2
    qpass12_kernel<<<13312, 256, 0, stream>>>(Bf, cs12 + 13 * 144, A);
    q4_kernel<<<16, 64, 0, stream>>>(Bf, cs4, A);
    gn1_kernel<<<1024, 160, 0, stream>>>(A, x, gn1s, gn1b, out);
}